// Round 11
// baseline (6654.784 us; speedup 1.0000x reference)
//
#include <hip/hip_runtime.h>
#include <hip/hip_fp16.h>

#define NN   514
#define BB   32
#define TT   2000
#define LT   101
#define LTT  50
#define NSL  10      // row-slices per direction
#define RS   56      // rows per slice
#define KPW  19      // payload qwords per batch-column (3 halves each -> 57>=56)
#define KPS  76      // padded k per slice (19*4)
#define PSTR 776     // P_lds row stride in halves (760 used + pad)
#define NQP  608     // payload qwords per slice message (19*32)
#define NQD  11      // dq qwords per slice message
#define NQS  619
#define NCH  (9*NQS) // 5571 chunks ingested per step
#define SPT  11      // chunks per thread (ceil 5571/512)
#define NEGV -1e30f
#define DSIZE 100352
#define PAR_STRIDE (2*NSL*NQS)

typedef unsigned long long ull;
typedef _Float16 f16x8 __attribute__((ext_vector_type(8)));
typedef float    f32x4 __attribute__((ext_vector_type(4)));

// ws offsets (bytes)
#define OFF_P  0          // ull PBQ[2 par][2 dir][10][619]  (198080 B)
#define OFF_A  200704     // float AOUT[32][514]
#define OFF_B  266496     // float BOUT[32][514]
#define OFF_FF 332288     // float FF[32][101]
#define OFF_FB 345216     // float FB[32][101]

// dynamic-LDS offsets (bytes). E-init region [0,99328) overlaps all steady
// arrays; E is dead after A-frags move to registers (barrier-separated).
#define L_P    0          // half  P[32][776]
#define L_PT   49664      // ushort ptmp[32][64]
#define L_CR   53760      // float cred[3][2][4][256]
#define L_MLS  78336      // float mls[10][32]
#define L_DQT  79616      // float dqtmp[10][32]
#define L_DQS  80896      // ushort dqstage[34]
#define L_BETL 81024      // float [104] (FAL WGs)

__device__ __forceinline__ ull apoll(const ull* p) {
  return __hip_atomic_load(p, __ATOMIC_RELAXED, __HIP_MEMORY_SCOPE_AGENT);
}
__device__ __forceinline__ void apub(ull* p, ull w) {
  __hip_atomic_store(p, w, __ATOMIC_RELAXED, __HIP_MEMORY_SCOPE_AGENT);
}
__device__ __forceinline__ void bar_lds() {
  asm volatile("s_waitcnt lgkmcnt(0)\n\ts_barrier" ::: "memory");
}

__global__ void k_reset(ull* q) {
  int i = blockIdx.x * 256 + threadIdx.x;
  if (i < 2 * 2 * NSL * NQS) q[i] = 0xFFFF000000000000ull;
}

extern "C" __global__ void __launch_bounds__(512, 2)
k_main(const float* __restrict__ inp, const float* __restrict__ tr,
       const int* __restrict__ tg, char* __restrict__ ws) {
  extern __shared__ char smem[];
  ull*   PBQ  = (ull*)(ws + OFF_P);
  float* AOUT = (float*)(ws + OFF_A);
  float* BOUT = (float*)(ws + OFF_B);
  float* FF   = (float*)(ws + OFF_FF);
  float* FB   = (float*)(ws + OFF_FB);

  const int bid = blockIdx.x;
  const int tid = threadIdx.x;

  if (bid < 2 * NSL) {
    // ================= FCC slice WG: all 32 batches, rows [r0, r0+nr) ======
    const int dir = bid / NSL;
    const int s   = bid % NSL;
    const int r0  = s * RS;
    const int nr  = (NN - r0 < RS) ? (NN - r0) : RS;
    const int ITER = dir ? (TT / 2 - 1) : (TT / 2);

    half*   Plds = (half*)(smem + L_P);
    unsigned short* ptmp = (unsigned short*)(smem + L_PT);
    float*  mlsp = (float*)(smem + L_MLS);
    float*  dqtp = (float*)(smem + L_DQT);
    unsigned short* dqs = (unsigned short*)(smem + L_DQS);

    // ---- build padded exp(E) slice in LDS (fp16), zeros at tag/pad cols ----
    {
      half* Elds = (half*)smem;
      for (int u = tid; u < 64 * PSTR; u += 512) {
        int row = u / PSTR, kp = u - row * PSTR;
        float v = 0.f;
        if (row < nr && kp < 760) {
          int sk = kp / KPS, rem = kp - sk * KPS;
          int j = rem >> 2, w = rem & 3;
          int kkl = 3 * j + w;
          if (w < 3 && kkl < RS) {
            int gc = sk * RS + kkl;
            if (gc < NN) {
              float wt = dir ? tr[(size_t)(1 + gc) * NN + (r0 + row)]
                             : tr[(size_t)(1 + r0 + row) * NN + gc];
              v = __expf(wt);
            }
          }
        }
        Elds[u] = __float2half(v);
      }
    }
    __syncthreads();

    const int l  = tid & 63;
    const int wv = tid >> 6;
    const int Nt = wv & 1;        // batch half (0..1)
    const int Ks = wv >> 1;       // K quarter (0..3)
    const bool epi = (Ks == 0);   // epilogue waves 0,1
    const int b  = Nt * 16 + (l & 15);    // batch for MFMA frags / epilogue
    const int rg = l >> 4;                // row-group

    // ---- E-slice A-fragments -> registers (E LDS region dead after this) ----
    f16x8 af[4][6];
    {
      const half* Elds = (const half*)smem;
      #pragma unroll
      for (int Mt = 0; Mt < 4; ++Mt)
        #pragma unroll
        for (int sl = 0; sl < 6; ++sl)
          af[Mt][sl] = *(const f16x8*)(Elds + (Mt * 16 + (l & 15)) * PSTR +
                                       (Ks * 6 + sl) * 32 + rg * 8);
    }
    __syncthreads();

    // ---- zero steady-state LDS ----
    for (int u = tid; u < 512; u += 512) { int bb = u >> 4; Plds[bb * PSTR + 760 + (u & 15)] = __float2half(0.f); }
    for (int u = tid; u < NSL * 32; u += 512) mlsp[u] = 0.f;
    if (tid == 0) { dqs[32] = 0; dqs[33] = 0; }

    // ---- per-thread chunk tables ----
    const ull* cbase[SPT]; int cdst[SPT]; int cmls[SPT]; bool cval[SPT], cdq[SPT];
    #pragma unroll
    for (int i = 0; i < SPT; ++i) {
      int f = tid + 512 * i;
      cval[i] = (f < NCH);
      int pi = cval[i] ? (f / NQS) : 0;
      int qq = cval[i] ? (f - pi * NQS) : 0;
      int sp = pi + (pi >= s ? 1 : 0);
      cdq[i] = (qq >= NQP);
      cbase[i] = PBQ + ((size_t)(0 * 2 + dir) * NSL + sp) * NQS + qq;
      if (!cdq[i]) {
        int bb = qq / KPW, j = qq - bb * KPW;
        cdst[i] = L_P + (bb * PSTR + sp * KPS + 4 * j) * 2;
        cmls[i] = 0;
      } else {
        cdst[i] = -1;
        cmls[i] = sp * 32 + 3 * (qq - NQP);
      }
    }

    const size_t ibase_b = (size_t)b * TT * NN;   // epilogue lanes' batch
    float m_run = 0.f, MhatCur = 0.f, mcPrev = 0.f;
    float aa[4][4];   // alpha per (Mt, reg) for epilogue lanes

    // ================= bootstrap (t = 0) =================
    if (epi) {
      #pragma unroll
      for (int Mt = 0; Mt < 4; ++Mt)
        #pragma unroll
        for (int rr = 0; rr < 4; ++rr) {
          int r = r0 + Mt * 16 + rg * 4 + rr;
          float v = NEGV;
          if (r < NN) {
            v = dir ? inp[ibase_b + (size_t)(TT - 1) * NN + r]
                    : (inp[ibase_b + r] + tr[r]);
          }
          aa[Mt][rr] = v;
        }
      float v = aa[0][0];
      #pragma unroll
      for (int Mt = 0; Mt < 4; ++Mt)
        #pragma unroll
        for (int rr = 0; rr < 4; ++rr) v = fmaxf(v, aa[Mt][rr]);
      v = fmaxf(v, __shfl_xor(v, 16));
      v = fmaxf(v, __shfl_xor(v, 32));
      __half dqh = __float2half(v);          // dq0 = v - 0
      m_run = __half2float(dqh);
      if (rg == 0) dqs[b] = __half_as_ushort(dqh);
    }
    bar_lds();
    // publish dq0 (tag 0, par 0)
    {
      ull* dst = PBQ + ((size_t)(0 * 2 + dir) * NSL + s) * NQS;
      if (tid >= 96 && tid < 96 + NQD) {
        int k0 = 3 * (tid - 96);
        ull w = (ull)dqs[k0] | ((ull)dqs[k0 + 1] << 16) | ((ull)dqs[k0 + 2] << 32);
        apub(dst + NQP + (tid - 96), w);
      }
    }
    // bootstrap spin: dq chunks only (tag 0) -> dqtmp
    {
      #pragma unroll
      for (int i = 0; i < SPT; ++i) {
        if (cval[i] && cdq[i]) {
          ull vq; int guard = 0;
          do { vq = apoll(cbase[i]); } while ((unsigned)(vq >> 48) != 0u && ++guard < (1 << 22));
          int b0 = cmls[i] & 31;
          #pragma unroll
          for (int kk = 0; kk < 3; ++kk)
            if (b0 + kk < 32)
              dqtp[cmls[i] + kk] = __half2float(__ushort_as_half((unsigned short)(vq >> (16 * kk))));
        }
      }
    }
    bar_lds();
    if (epi) {
      float mc = m_run;
      #pragma unroll
      for (int sp = 0; sp < NSL; ++sp)
        if (sp != s) mc = fmaxf(mc, dqtp[sp * 32 + b]);
      MhatCur = mc;                       // Phi_0
      #pragma unroll
      for (int Mt = 0; Mt < 4; ++Mt) {
        unsigned lo = __half_as_ushort(__float2half(__expf(aa[Mt][0] - mc))) |
                      ((unsigned)__half_as_ushort(__float2half(__expf(aa[Mt][1] - mc))) << 16);
        unsigned hi = __half_as_ushort(__float2half(__expf(aa[Mt][2] - mc))) |
                      ((unsigned)__half_as_ushort(__float2half(__expf(aa[Mt][3] - mc))) << 16);
        *(ull*)(smem + L_PT + (b * 64 + Mt * 16 + rg * 4) * 2) = (ull)lo | ((ull)hi << 32);
      }
    }
    bar_lds();
    // publish payload p0 (tag 0, par 0) + local copy into own P region
    {
      ull* dst = PBQ + ((size_t)(0 * 2 + dir) * NSL + s) * NQS;
      #pragma unroll
      for (int rep = 0; rep < 2; ++rep) {
        int q = tid + 512 * rep;
        if (q < NQP) {
          int bb = q / KPW, j = q - bb * KPW;
          ull w = (ull)ptmp[bb * 64 + 3 * j] | ((ull)ptmp[bb * 64 + 3 * j + 1] << 16) |
                  ((ull)ptmp[bb * 64 + 3 * j + 2] << 32);
          *(ull*)(smem + L_P + (bb * PSTR + s * KPS + 4 * j) * 2) = w;
          apub(dst + q, w);
        }
      }
    }

    // ================= main loop =================
    for (int t = 1; t <= ITER; ++t) {
      // e prefetch for this step (epilogue lanes)
      float ev[4][4];
      if (epi) {
        int et = dir ? (TT - 1 - t) : t;
        #pragma unroll
        for (int Mt = 0; Mt < 4; ++Mt) {
          int rlo = r0 + Mt * 16 + rg * 4;
          const float* pe = inp + ibase_b + (size_t)et * NN + rlo;
          if (rlo + 1 < NN) { ev[Mt][0] = pe[0]; ev[Mt][1] = pe[1]; } else { ev[Mt][0] = 0; ev[Mt][1] = 0; }
          if (rlo + 3 < NN) { ev[Mt][2] = pe[2]; ev[Mt][3] = pe[3]; } else { ev[Mt][2] = 0; ev[Mt][3] = 0; }
        }
      }

      const unsigned want = (unsigned)((t - 1) & 0xffff);
      const size_t pofs = (size_t)((t - 1) & 1) * PAR_STRIDE;

      // ---- spin + scatter (self-validating qwords; raw copy into LDS) ----
      {
        bool pend[SPT]; ull vv[SPT];
        #pragma unroll
        for (int i = 0; i < SPT; ++i) { pend[i] = cval[i]; if (pend[i]) vv[i] = apoll(cbase[i] + pofs); }
        int guard = 0; bool any = true;
        while (any) {
          any = false;
          #pragma unroll
          for (int i = 0; i < SPT; ++i) if (pend[i]) {
            if ((unsigned)(vv[i] >> 48) == want) {
              pend[i] = false;
              if (!cdq[i]) {
                *(ull*)(smem + cdst[i]) = vv[i];       // tag half lands on zero-E col
              } else {
                int b0 = cmls[i] & 31;
                #pragma unroll
                for (int kk = 0; kk < 3; ++kk)
                  if (b0 + kk < 32)
                    mlsp[cmls[i] + kk] += __half2float(__ushort_as_half((unsigned short)(vv[i] >> (16 * kk))));
              }
            } else { vv[i] = apoll(cbase[i] + pofs); any = true; }
          }
          if (++guard > (1 << 20)) break;
        }
      }
      bar_lds();                                     // A: P + mls ready

      // ---- MFMA: c[Mt] += E(af) x P, K-quarter Ks ----
      f32x4 c[4] = {};
      {
        const half* prow = Plds + (Nt * 16 + (l & 15)) * PSTR + rg * 8 + Ks * 192;
        #pragma unroll
        for (int sl = 0; sl < 6; ++sl) {
          f16x8 bf = *(const f16x8*)(prow + sl * 32);
          #pragma unroll
          for (int Mt = 0; Mt < 4; ++Mt)
            c[Mt] = __builtin_amdgcn_mfma_f32_16x16x32_f16(af[Mt][sl], bf, c[Mt], 0, 0, 0);
        }
      }
      if (Ks > 0) {
        #pragma unroll
        for (int Mt = 0; Mt < 4; ++Mt)
          *(f32x4*)(smem + L_CR + ((((Ks - 1) * 2 + Nt) * 4 + Mt) * 256 + l * 4) * 4) = c[Mt];
      }
      bar_lds();                                     // B: cred ready

      // ---- epilogue (waves 0,1) ----
      if (epi) {
        float mc = m_run;
        #pragma unroll
        for (int sp = 0; sp < NSL; ++sp)
          if (sp != s) mc = fmaxf(mc, mlsp[sp * 32 + b]);
        float phi = (t == 1) ? (mc + 7.0f) : (2.0f * mc - mcPrev);
        mcPrev = mc;

        float vmax = NEGV;
        #pragma unroll
        for (int Mt = 0; Mt < 4; ++Mt) {
          f32x4 cs = c[Mt];
          #pragma unroll
          for (int ks = 1; ks < 4; ++ks)
            cs += *(const f32x4*)(smem + L_CR + ((((ks - 1) * 2 + Nt) * 4 + Mt) * 256 + l * 4) * 4);
          #pragma unroll
          for (int rr = 0; rr < 4; ++rr) {
            float a = ev[Mt][rr] + MhatCur + __logf(cs[rr]);
            aa[Mt][rr] = a;
            vmax = fmaxf(vmax, a);
          }
        }
        vmax = fmaxf(vmax, __shfl_xor(vmax, 16));
        vmax = fmaxf(vmax, __shfl_xor(vmax, 32));
        __half dqh = __float2half(vmax - m_run);
        m_run += __half2float(dqh);
        if (rg == 0) dqs[b] = __half_as_ushort(dqh);

        #pragma unroll
        for (int Mt = 0; Mt < 4; ++Mt) {
          unsigned lo = __half_as_ushort(__float2half(__expf(aa[Mt][0] - phi))) |
                        ((unsigned)__half_as_ushort(__float2half(__expf(aa[Mt][1] - phi))) << 16);
          unsigned hi = __half_as_ushort(__float2half(__expf(aa[Mt][2] - phi))) |
                        ((unsigned)__half_as_ushort(__float2half(__expf(aa[Mt][3] - phi))) << 16);
          *(ull*)(smem + L_PT + (b * 64 + Mt * 16 + rg * 4) * 2) = (ull)lo | ((ull)hi << 32);
        }
        if (t == ITER) {
          #pragma unroll
          for (int Mt = 0; Mt < 4; ++Mt)
            #pragma unroll
            for (int rr = 0; rr < 4; ++rr) {
              int r = r0 + Mt * 16 + rg * 4 + rr;
              if (r < NN) {
                if (!dir) AOUT[b * NN + r] = aa[Mt][rr];
                else      BOUT[b * NN + r] = aa[Mt][rr] - ev[Mt][rr];
              }
            }
        }
        MhatCur = phi;
      }
      bar_lds();                                     // C: ptmp + dqs ready

      // ---- publish (tag t, par t&1) + own-slice local P copy ----
      {
        ull* dst = PBQ + ((size_t)((t & 1) * 2 + dir) * NSL + s) * NQS;
        const ull tagw = (ull)(t & 0xffff) << 48;
        #pragma unroll
        for (int rep = 0; rep < 2; ++rep) {
          int q = tid + 512 * rep;
          if (q < NQP) {
            int bb = q / KPW, j = q - bb * KPW;
            ull w = (ull)ptmp[bb * 64 + 3 * j] | ((ull)ptmp[bb * 64 + 3 * j + 1] << 16) |
                    ((ull)ptmp[bb * 64 + 3 * j + 2] << 32) | tagw;
            *(ull*)(smem + L_P + (bb * PSTR + s * KPS + 4 * j) * 2) = w;
            apub(dst + q, w);
          }
        }
        if (tid >= 96 && tid < 96 + NQD) {
          int k0 = 3 * (tid - 96);
          ull w = (ull)dqs[k0] | ((ull)dqs[k0 + 1] << 16) | ((ull)dqs[k0 + 2] << 32) | tagw;
          apub(dst + NQP + (tid - 96), w);
        }
      }
    }
  } else {
    // ================= FAL WG (one per batch per direction) =================
    const int idx = bid - 2 * NSL;
    const int dir = idx >> 5;
    const int b   = idx & 31;
    const int l   = tid;
    float* betl = (float*)(smem + L_BETL);
    const size_t ibase = (size_t)b * TT * NN;
    const int ITER = dir ? (TT / 2 - 1) : (TT / 2);

    int   tgtl = NN - 1, tgtl1 = NN - 1;
    float self_w = 0.f, move_w = NEGV, move1 = NEGV, fbeta = NEGV;
    float em0 = 0.f, em1 = 0.f;
    if (l < 104) betl[l] = NEGV;
    if (l < LT) {
      tgtl = (l & 1) ? (tg[b * LTT + (l >> 1)] + 1) : (NN - 1);
      self_w = tr[(size_t)(1 + tgtl) * NN + tgtl];
      if (!dir) {
        if (l > 0) {
          int tgtm = ((l - 1) & 1) ? (tg[b * LTT + ((l - 1) >> 1)] + 1) : (NN - 1);
          move_w = tr[(size_t)(1 + tgtl) * NN + tgtm];
        }
        fbeta = (l == 0) ? (inp[ibase + (NN - 1)] + tr[NN - 1]) : NEGV;
        em0 = inp[ibase + (size_t)1 * NN + tgtl];
      } else {
        if (l < LT - 1) {
          tgtl1 = ((l + 1) & 1) ? (tg[b * LTT + ((l + 1) >> 1)] + 1) : (NN - 1);
          move1 = tr[(size_t)(1 + tgtl1) * NN + tgtl];
        }
        fbeta = (l == LT - 1) ? 0.f : NEGV;
        em0 = inp[ibase + (size_t)(TT - 1) * NN + tgtl];
        em1 = inp[ibase + (size_t)(TT - 1) * NN + tgtl1];
      }
      betl[l] = fbeta;
    }
    __syncthreads();

    for (int t = 1; t <= ITER; ++t) {
      float fnb = 0.f;
      if (l < LT) {
        if (!dir) {
          float bprev = (l > 0) ? betl[l - 1] : NEGV;
          float v1 = fbeta + self_w, v2 = bprev + move_w;
          float mx = fmaxf(v1, v2), mn = fminf(v1, v2);
          fnb = em0 + mx + __logf(1.f + __expf(mn - mx));
        } else {
          float bnx = betl[l + 1];
          float v1 = self_w + em0 + fbeta;
          float v2 = move1 + em1 + bnx;
          float mx = fmaxf(v1, v2), mn = fminf(v1, v2);
          fnb = mx + __logf(1.f + __expf(mn - mx));
        }
      }
      bar_lds();
      if (l < LT) {
        betl[l] = fnb; fbeta = fnb;
        int ti = dir ? (TT - 1 - t) : (t + 1);
        if (ti < 0) ti = 0;
        if (ti > TT - 1) ti = TT - 1;
        em0 = inp[ibase + (size_t)ti * NN + tgtl];
        if (dir) em1 = inp[ibase + (size_t)ti * NN + tgtl1];
      }
      bar_lds();
      if (t == ITER && l < LT) {
        if (!dir) FF[b * LT + l] = fbeta;
        else      FB[b * LT + l] = fbeta;
      }
    }
  }
}

__global__ void k_fin(const char* __restrict__ ws, float* __restrict__ out) {
  const float* A   = (const float*)(ws + OFF_A);
  const float* B   = (const float*)(ws + OFF_B);
  const float* FFp = (const float*)(ws + OFF_FF);
  const float* FBp = (const float*)(ws + OFF_FB);
  int tid = threadIdx.x;
  float v = 0.f;
  if (tid < BB) {
    float m = NEGV;
    for (int r = 0; r < NN; ++r) m = fmaxf(m, A[tid * NN + r] + B[tid * NN + r]);
    float sum = 0.f;
    for (int r = 0; r < NN; ++r) sum += __expf(A[tid * NN + r] + B[tid * NN + r] - m);
    float fcc = m + __logf(sum);
    float m2 = NEGV;
    for (int k = 0; k < LT; ++k) m2 = fmaxf(m2, FFp[tid * LT + k] + FBp[tid * LT + k]);
    float s2 = 0.f;
    for (int k = 0; k < LT; ++k) s2 += __expf(FFp[tid * LT + k] + FBp[tid * LT + k] - m2);
    float fal = m2 + __logf(s2);
    v = (fcc - fal) * (1.0f / (float)LT);
  }
  for (int mm = 1; mm < 64; mm <<= 1) v += __shfl_xor(v, mm);
  if (tid == 0) out[0] = v / (float)BB;
}

extern "C" void kernel_launch(void* const* d_in, const int* in_sizes, int n_in,
                              void* d_out, int out_size, void* d_ws, size_t ws_size,
                              hipStream_t stream) {
  const float* inp = (const float*)d_in[0];
  const float* tr  = (const float*)d_in[1];
  const int*   tg  = (const int*)d_in[2];
  float* out = (float*)d_out;
  char*  ws  = (char*)d_ws;

  (void)hipFuncSetAttribute(reinterpret_cast<const void*>(k_main),
                            hipFuncAttributeMaxDynamicSharedMemorySize, DSIZE);

  k_reset<<<dim3(97), dim3(256), 0, stream>>>((ull*)(ws + OFF_P));
  k_main<<<dim3(2 * NSL + 64), dim3(512), DSIZE, stream>>>(inp, tr, tg, ws);
  k_fin<<<dim3(1), dim3(64), 0, stream>>>(ws, out);
}

// Round 12
// 4673.772 us; speedup vs baseline: 1.4239x; 1.4239x over previous
//
#include <hip/hip_runtime.h>
#include <hip/hip_fp16.h>

// Problem constants
#define NN   514      // states
#define BB   32
#define TT   2000
#define LT   101      // 2*Lt+1
#define LTT  50
#define NSL  11       // slices per batch per direction
#define RS   47       // rows per slice (11*47=517 >= 514)
#define RSTR 520      // LDS row stride (halves)
#define QW   16       // tagged qwords per slice (3 fp16 each; dq in qw15.h2)
#define NEGV -1e30f

typedef unsigned long long ull;

// ws offsets
#define OFF_P    0                    // ull PBQ[2par][2dir][32][11][16] (180224 B)
#define OFF_A    180224               // float AOUT[32][514] (65792 B)
#define OFF_B    246016               // float BOUT[32][514] (65792 B)
#define OFF_FF   311808               // float FF[32][101]   (12928 B)
#define OFF_FB   324736               // float FB[32][101]   (12928 B)

typedef _Float16 h2t __attribute__((ext_vector_type(2)));

#if defined(__has_builtin)
#if __has_builtin(__builtin_amdgcn_fdot2)
#define HAVE_FDOT2 1
#endif
#endif
#ifndef HAVE_FDOT2
#define HAVE_FDOT2 0
#endif

__device__ __forceinline__ float dot2acc(unsigned a, unsigned b, float c) {
#if HAVE_FDOT2
  return __builtin_amdgcn_fdot2(__builtin_bit_cast(h2t, a),
                                __builtin_bit_cast(h2t, b), c, false);
#else
  h2t ha = __builtin_bit_cast(h2t, a), hb = __builtin_bit_cast(h2t, b);
  c += (float)ha[0] * (float)hb[0];
  c += (float)ha[1] * (float)hb[1];
  return c;
#endif
}

__device__ __forceinline__ ull apoll(const ull* p) {
  return __hip_atomic_load(p, __ATOMIC_RELAXED, __HIP_MEMORY_SCOPE_AGENT);
}

// LDS-only barrier (does NOT drain vmcnt; publish stores stay in flight)
__device__ __forceinline__ void bar_lds() {
  asm volatile("s_waitcnt lgkmcnt(0)\n\ts_barrier" ::: "memory");
}

__global__ void k_reset(ull* q) {
  int i = blockIdx.x * 256 + threadIdx.x;
  if (i < 2 * 2 * BB * NSL * QW) q[i] = 0xFFFF000000000000ull;
}

__global__ __launch_bounds__(384, 5) void k_main(const float* __restrict__ inp,
                                                 const float* __restrict__ tr,
                                                 const int* __restrict__ tg,
                                                 char* __restrict__ ws) {
  ull*   PBQ  = (ull*)(ws + OFF_P);
  float* AOUT = (float*)(ws + OFF_A);
  float* BOUT = (float*)(ws + OFF_B);
  float* FF   = (float*)(ws + OFF_FF);
  float* FB   = (float*)(ws + OFF_FB);

  __shared__ __align__(16) __half expw[RS * RSTR];   // 48880 B
  __shared__ __align__(16) __half pall[544];         // 1088 B
  __shared__ unsigned short ptmp[64];
  __shared__ float mlsL[12];
  __shared__ float dpart[4][64];
  __shared__ float betl[104];
  __shared__ float bbL[104];

  const int bid = blockIdx.x;
  const int tid = threadIdx.x;
  const int dir = bid / (NSL * BB);          // 0 = forward, 1 = backward
  const int rem = bid - dir * (NSL * BB);
  const int s   = rem >> 5;
  const int b   = rem & 31;
  const int r0  = s * RS;
  const int nr  = (NN - r0 < RS) ? (NN - r0) : RS;
  const int ITER = dir ? (TT / 2 - 1) : (TT / 2);   // 999 : 1000 (meet at 1000)
  const size_t ibase = (size_t)b * TT * NN;

  // ---- stage exp(transmat) slice (transposed for backward) ----
  for (int uu = tid; uu < RS * RSTR; uu += 384) {
    int jj = uu / RSTR, c = uu - jj * RSTR;
    float v = 0.f;
    if (jj < nr && c < NN) {
      float w = dir ? tr[(size_t)(1 + c) * NN + (r0 + jj)]
                    : tr[(size_t)(1 + r0 + jj) * NN + c];
      v = __expf(w);
    }
    expw[uu] = __float2half(v);
  }
  for (int uu = tid; uu < 544; uu += 384) pall[uu] = __float2half(0.f);
  if (tid < 64) ptmp[tid] = 0;
  if (tid < 12) mlsL[tid] = 0.f;

  // ---- FAL setup (waves 4-5 of s==0 WGs) ----
  const bool falWG = (s == 0);
  const int  l     = tid - 256;                     // 0..127 in waves 4-5
  const bool falT  = falWG && (tid >= 256) && (l < LT);
  int   tgtl = NN - 1, tgtl1 = NN - 1;
  float self_w = 0.f, move_w = NEGV, move1 = NEGV;
  float fbeta = NEGV;
  float em0 = 0.f, em1 = 0.f;
  if (falT) {
    tgtl = (l & 1) ? (tg[b * LTT + (l >> 1)] + 1) : (NN - 1);
    self_w = tr[(size_t)(1 + tgtl) * NN + tgtl];
    if (!dir) {
      if (l > 0) {
        int tgtm = ((l - 1) & 1) ? (tg[b * LTT + ((l - 1) >> 1)] + 1) : (NN - 1);
        move_w = tr[(size_t)(1 + tgtl) * NN + tgtm];
      }
      fbeta = (l == 0) ? (inp[ibase + (NN - 1)] + tr[NN - 1]) : NEGV;
      betl[l] = fbeta;
      em0 = inp[ibase + (size_t)1 * NN + tgtl];
    } else {
      if (l < LT - 1) {
        tgtl1 = ((l + 1) & 1) ? (tg[b * LTT + ((l + 1) >> 1)] + 1) : (NN - 1);
        move1 = tr[(size_t)(1 + tgtl1) * NN + tgtl];
      }
      fbeta = (l == LT - 1) ? 0.f : NEGV;
      bbL[l] = fbeta;
      em0 = inp[ibase + (size_t)(TT - 1) * NN + tgtl];
      em1 = inp[ibase + (size_t)(TT - 1) * NN + tgtl1];
    }
  }
  if (tid >= 256 && l >= LT && l < 104) { betl[l] = NEGV; bbL[l] = NEGV; }
  __syncthreads();

  // ---- FCC thread roles ----
  const int  row   = tid & 63;
  const int  q     = tid >> 6;          // wave id
  const bool fcc   = (tid < 256);
  const bool w0    = (q == 0);
  const bool rowOK = fcc && (row < nr);
  const int  iters = (q == 3) ? 14 : 17;       // q*136 cols, 514 total

  const int  u    = tid - 64;                  // pollers: waves 1-3
  const bool act  = fcc && (u >= 0) && (u < (NSL - 1) * QW);  // 160
  const int  spe  = act ? (u >> 4) : 0;
  const int  idx  = u & 15;
  const int  sp   = act ? (spe >= s ? spe + 1 : spe) : 0;
  const int  dql  = ((u >> 4) & 3) * 16 + 15;

  // CONTENTION FIX 1: wave 0 (serial tail + publish = critical path) wins
  // CU issue arbitration against co-resident WGs' spin waves.
  if (w0) __builtin_amdgcn_s_setprio(1);

  float mrun_sl = 0.f, m_run = 0.f, pval = 0.f, e_reg = 0.f;
  unsigned short dq_bits = 0;
  float Mhat = 4.0f, Mprev = 0.f;

  // ---- t=0: wave0 init + publish (tag 0) ----
  if (w0) {
    float v0 = NEGV;
    if (rowOK) {
      v0 = inp[ibase + (dir ? (size_t)(TT - 1) * NN : 0) + (r0 + row)];
      if (!dir) v0 += tr[r0 + row];
    }
    float v = v0;
    #pragma unroll
    for (int mm = 1; mm < 64; mm <<= 1) v = fmaxf(v, __shfl_xor(v, mm));
    __half dqh = __float2half(v - m_run);
    m_run += __half2float(dqh);
    dq_bits = __half_as_ushort(dqh);
    pval = rowOK ? __expf(v0 - m_run) : 0.f;
    ptmp[row] = rowOK ? __half_as_ushort(__float2half(pval)) : (unsigned short)0;
    if (tid < QW) {
      unsigned short h0 = ptmp[3 * tid];
      unsigned short h1 = ptmp[3 * tid + 1];
      unsigned short h2 = (tid == QW - 1) ? dq_bits : ptmp[3 * tid + 2];
      ull w = (ull)h0 | ((ull)h1 << 16) | ((ull)h2 << 32);  // tag 0
      __hip_atomic_store(&PBQ[((((size_t)0 * 2 + dir) * BB + b) * NSL + s) * QW + tid],
                         w, __ATOMIC_RELAXED, __HIP_MEMORY_SCOPE_AGENT);
    }
    if (rowOK) {
      int ti = dir ? (TT - 2) : 1;
      e_reg = inp[ibase + (size_t)ti * NN + (r0 + row)];
    }
  }

  // ---- main loop: 1000 fwd / 999 bwd sequential exchanges ----
  for (int t = 1; t <= ITER; ++t) {
    float e_nxt = 0.f;
    if (w0 && rowOK) {
      int tn = dir ? (TT - 2 - t) : (t + 1);
      if (tn < 0) tn = 0;
      if (tn > TT - 1) tn = TT - 1;
      e_nxt = inp[ibase + (size_t)tn * NN + (r0 + row)];
    }

    const unsigned want = (unsigned)((t - 1) & 0xffff);
    const int par = (t - 1) & 1;

    ull vq = 0;
    if (act) {
      const ull* src = &PBQ[((((size_t)par * 2 + dir) * BB + b) * NSL + sp) * QW + idx];
      ull a0 = apoll(src), a1 = apoll(src);
      int guard = 0;
      while ((unsigned)(a0 >> 48) != want && ++guard < (1 << 22)) {
        // CONTENTION FIX 2: back off ~64 cy between polls — cuts this wave's
        // issue pressure ~10x; adds <=64 cy expected latency vs ~900 cy RT.
        __builtin_amdgcn_s_sleep(1);
        ull a2 = apoll(src); a0 = a1; a1 = a2;   // depth-3 issue-before-check
      }
      vq = a0;
      if (idx == QW - 1)
        mrun_sl += __half2float(__ushort_as_half((unsigned short)(vq >> 32)));
    }

    // scatter (Mhat-centered; no barrier needed before it)
    if (fcc && q >= 1) {
      float mnew = __shfl(mrun_sl, dql);
      if (act) {
        float scale = __expf(mnew - Mhat);
        #pragma unroll
        for (int kk = 0; kk < 3; ++kk) {
          int jj = 3 * idx + kk;
          if (jj < RS) {
            float pv = __half2float(__ushort_as_half((unsigned short)(vq >> (16 * kk)))) * scale;
            pall[sp * RS + jj] = __float2half(pv);
          }
        }
        if (idx == QW - 1) mlsL[sp] = mnew;
      }
    } else if (w0) {
      float scale = __expf(m_run - Mhat);
      if (tid < QW) {
        #pragma unroll
        for (int kk = 0; kk < 3; ++kk) {
          int jj = 3 * tid + kk;
          if (jj < RS) {
            float pv = __half2float(__ushort_as_half(ptmp[jj])) * scale;
            pall[s * RS + jj] = __float2half(pv);
          }
        }
      }
      if (tid == 0) mlsL[s] = m_run;
    }

    // FAL compute phase
    float fnb = 0.f;
    if (falT) {
      if (!dir) {
        float bprev = (l > 0) ? betl[l - 1] : NEGV;
        float v1 = fbeta + self_w, v2 = bprev + move_w;
        float mx = fmaxf(v1, v2), mn = fminf(v1, v2);
        fnb = em0 + mx + __logf(1.f + __expf(mn - mx));
      } else {
        float bnx = bbL[l + 1];
        float v1 = self_w + em0 + fbeta;
        float v2 = move1 + em1 + bnx;
        float mx = fmaxf(v1, v2), mn = fminf(v1, v2);
        fnb = mx + __logf(1.f + __expf(mn - mx));
      }
    }
    bar_lds();                                   // bar1: pall + mlsL ready

    // matvec
    float d = 0.f;
    if (rowOK) {
      const uint4* mp = (const uint4*)(expw + row * RSTR + q * 136);
      const uint4* pp = (const uint4*)(pall + q * 136);
      for (int k = 0; k < iters; ++k) {
        uint4 mm = mp[k], pv = pp[k];
        d = dot2acc(mm.x, pv.x, d);
        d = dot2acc(mm.y, pv.y, d);
        d = dot2acc(mm.z, pv.z, d);
        d = dot2acc(mm.w, pv.w, d);
      }
    }
    if (fcc) dpart[q][row] = d;

    // Mhat tracking (in matvec window)
    float Mnext = Mhat;
    if (fcc) {
      float Mc = mlsL[0];
      #pragma unroll
      for (int k = 1; k < NSL; ++k) Mc = fmaxf(Mc, mlsL[k]);
      Mnext = (t == 1) ? (Mc + 7.0f) : (2.0f * Mc - Mprev);
      Mprev = Mc;
    }

    // FAL write + em prefetch
    if (falT) {
      if (!dir) betl[l] = fnb; else bbL[l] = fnb;
      fbeta = fnb;
      int ti = dir ? (TT - 1 - t) : (t + 1);
      if (ti < 0) ti = 0;
      if (ti > TT - 1) ti = TT - 1;
      em0 = inp[ibase + (size_t)ti * NN + tgtl];
      if (dir) em1 = inp[ibase + (size_t)ti * NN + tgtl1];
    }
    bar_lds();                                   // bar2: dpart (+FAL state) ready

    // wave0 serial tail; waves 1-3 loop back to poll immediately
    if (w0) {
      float dsum = dpart[0][row] + dpart[1][row] + dpart[2][row] + dpart[3][row];
      float val = rowOK ? (e_reg + Mhat + __logf(dsum)) : NEGV;
      float v = val;
      #pragma unroll
      for (int mm = 1; mm < 64; mm <<= 1) v = fmaxf(v, __shfl_xor(v, mm));
      __half dqh = __float2half(v - m_run);
      m_run += __half2float(dqh);
      dq_bits = __half_as_ushort(dqh);
      pval = rowOK ? __expf(val - m_run) : 0.f;
      ptmp[row] = rowOK ? __half_as_ushort(__float2half(pval)) : (unsigned short)0;
      if (tid < QW) {
        unsigned short h0 = ptmp[3 * tid];
        unsigned short h1 = ptmp[3 * tid + 1];
        unsigned short h2 = (tid == QW - 1) ? dq_bits : ptmp[3 * tid + 2];
        ull w = (ull)h0 | ((ull)h1 << 16) | ((ull)h2 << 32) |
                ((ull)(t & 0xffff) << 48);
        __hip_atomic_store(&PBQ[((((size_t)(t & 1) * 2 + dir) * BB + b) * NSL + s) * QW + tid],
                           w, __ATOMIC_RELAXED, __HIP_MEMORY_SCOPE_AGENT);
      }
      if (t == ITER && rowOK) {
        if (!dir) AOUT[b * NN + r0 + row] = val;            // alpha_1000
        else      BOUT[b * NN + r0 + row] = val - e_reg;    // beta_1000 (strip e)
      }
      e_reg = e_nxt;
    }
    if (t == ITER && falT) {
      if (!dir) FF[b * LT + l] = fbeta;   // bf_1000
      else      FB[b * LT + l] = fbeta;   // bb_1000
    }
    Mhat = Mnext;
  }
}

__global__ void k_fin(const char* __restrict__ ws, float* __restrict__ out) {
  const float* A  = (const float*)(ws + OFF_A);
  const float* B  = (const float*)(ws + OFF_B);
  const float* FFp = (const float*)(ws + OFF_FF);
  const float* FBp = (const float*)(ws + OFF_FB);
  int tid = threadIdx.x;
  float v = 0.f;
  if (tid < BB) {
    float m = NEGV;
    for (int r = 0; r < NN; ++r) m = fmaxf(m, A[tid * NN + r] + B[tid * NN + r]);
    float sum = 0.f;
    for (int r = 0; r < NN; ++r) sum += __expf(A[tid * NN + r] + B[tid * NN + r] - m);
    float fcc = m + __logf(sum);
    float m2 = NEGV;
    for (int k = 0; k < LT; ++k) m2 = fmaxf(m2, FFp[tid * LT + k] + FBp[tid * LT + k]);
    float s2 = 0.f;
    for (int k = 0; k < LT; ++k) s2 += __expf(FFp[tid * LT + k] + FBp[tid * LT + k] - m2);
    float fal = m2 + __logf(s2);
    v = (fcc - fal) * (1.0f / (float)LT);
  }
  for (int mm = 1; mm < 64; mm <<= 1) v += __shfl_xor(v, mm);
  if (tid == 0) out[0] = v / (float)BB;
}

extern "C" void kernel_launch(void* const* d_in, const int* in_sizes, int n_in,
                              void* d_out, int out_size, void* d_ws, size_t ws_size,
                              hipStream_t stream) {
  const float* inp = (const float*)d_in[0];
  const float* tr  = (const float*)d_in[1];
  const int*   tg  = (const int*)d_in[2];
  float* out = (float*)d_out;
  char*  ws  = (char*)d_ws;

  k_reset<<<dim3(88), dim3(256), 0, stream>>>((ull*)(ws + OFF_P));
  k_main<<<dim3(2 * NSL * BB), dim3(384), 0, stream>>>(inp, tr, tg, ws);
  k_fin<<<dim3(1), dim3(64), 0, stream>>>(ws, out);
}